// Round 3
// baseline (1265.021 us; speedup 1.0000x reference)
//
#include <hip/hip_runtime.h>
#include <math.h>

// Router: logits = z @ W^T + b ; top-2 sparse softmax per row.
// z: [N=8192, D=4096] fp32, W: [K=64, D=4096] fp32, b: [64] fp32, k=2.
//
// R3: dataflow flip. R2 (lane=col) had a structural 80 us LDS floor: every
// wave re-read 1 MB of W from LDS (ds_read_b128 * 1024 * 1KB, 16 waves/CU
// -> 16 MB/CU at 85 B/cyc). Now lane = z-ROW: z staged coalesced in LDS and
// read conflict-free per-lane (stride 65: bank (l+k)%32); W becomes the
// wave-uniform operand read straight from global (L1/L2-resident, 1 MB) as
// broadcast float4 W[c][k..k+3] -> 4 FMAs per 16B. Split-K x4 across blocks
// (grid 512 = 128 rowgroups x 4 kq, 2 blocks/CU, 16 waves/CU), partials in
// d_ws (8 MB), small reduce kernel for sum + bias + top-2 + softmax.

constexpr int D_DIM = 4096;
constexpr int K_DIM = 64;     // output columns
constexpr int RG    = 64;     // rows per block (= lanes)
constexpr int CH    = 64;     // k per staged chunk
constexpr int KQ    = 4;      // split-K factor across blocks
constexpr int KRANGE = D_DIM / KQ;          // 1024
constexpr int NCHUNK = KRANGE / CH;         // 16
constexpr int BLOCK  = 512;                 // 8 waves: 4 col-tiles x 2 k-halves

__global__ __launch_bounds__(BLOCK, 4) void gemm_partial(
    const float* __restrict__ z, const float* __restrict__ W,
    float* __restrict__ part)
{
    __shared__ float zs[RG][CH + 1];        // stride 65: (65l+k)%32=(l+k)%32 -> 2-way max (free)

    const int tid  = threadIdx.x;
    const int lane = tid & 63;              // = local row
    const int wv   = tid >> 6;              // 0..7
    const int ct   = wv & 3;                // col-tile: cols ct*16..+15
    const int ks   = wv >> 2;               // 0/1: k-half within chunk
    const int rg   = blockIdx.x >> 2;       // row group
    const int kq   = blockIdx.x & 3;        // k quarter

    const float* zbase = z + (long)rg * RG * D_DIM;
    const int    kbase = kq * KRANGE;

    float acc[16];
#pragma unroll
    for (int c = 0; c < 16; ++c) acc[c] = 0.f;

    for (int ch = 0; ch < NCHUNK; ++ch) {
        const int k0 = kbase + ch * CH;
        // stage z[64 rows][64 k] -> zs, coalesced 16B reads (16 lanes / row)
#pragma unroll
        for (int i = 0; i < (RG * CH) / (BLOCK * 4); ++i) {     // 2 iters
            int f = tid + i * BLOCK;
            int r = f >> 4, kq4 = f & 15;
            const float4 v = *(const float4*)(zbase + (long)r * D_DIM + k0 + kq4 * 4);
            zs[r][kq4 * 4 + 0] = v.x;
            zs[r][kq4 * 4 + 1] = v.y;
            zs[r][kq4 * 4 + 2] = v.z;
            zs[r][kq4 * 4 + 3] = v.w;
        }
        __syncthreads();

        // compute this wave's k-half: 32 k x 16 cols
#pragma unroll
        for (int k4 = 0; k4 < 8; ++k4) {
            const int k = ks * 32 + k4 * 4;
            const float z0 = zs[lane][k + 0];
            const float z1 = zs[lane][k + 1];
            const float z2 = zs[lane][k + 2];
            const float z3 = zs[lane][k + 3];
            const float* wp = W + (long)(ct * 16) * D_DIM + k0 + k;
#pragma unroll
            for (int c = 0; c < 16; ++c) {
                // wave-uniform broadcast load, W row-major: W[c][k..k+3]
                const float4 wvv = *(const float4*)(wp + (long)c * D_DIM);
                acc[c] = fmaf(wvv.x, z0, acc[c]);
                acc[c] = fmaf(wvv.y, z1, acc[c]);
                acc[c] = fmaf(wvv.z, z2, acc[c]);
                acc[c] = fmaf(wvv.w, z3, acc[c]);
            }
        }
        __syncthreads();
    }

    // combine the two k-halves through LDS (reuse zs as logits[64][65])
    if (ks == 0) {
#pragma unroll
        for (int c = 0; c < 16; ++c) zs[lane][ct * 16 + c] = acc[c];
    }
    __syncthreads();
    if (ks == 1) {
#pragma unroll
        for (int c = 0; c < 16; ++c) zs[lane][ct * 16 + c] += acc[c];
    }
    __syncthreads();

    // store partial tile [64][64], coalesced
    float* pb = part + (long)blockIdx.x * (RG * K_DIM);
#pragma unroll
    for (int i = 0; i < (RG * K_DIM) / (BLOCK * 4); ++i) {      // 2 iters
        int f = tid + i * BLOCK;
        int r = f >> 4, c4 = (f & 15) * 4;
        float4 v;
        v.x = zs[r][c4 + 0]; v.y = zs[r][c4 + 1];
        v.z = zs[r][c4 + 2]; v.w = zs[r][c4 + 3];
        *(float4*)(pb + r * K_DIM + c4) = v;
    }
}

__global__ __launch_bounds__(BLOCK) void reduce_topk(
    const float* __restrict__ part, const float* __restrict__ bias,
    float* __restrict__ out)
{
    __shared__ float lg[RG][K_DIM + 1];
    __shared__ float sa1[RG], sa2[RG];
    __shared__ int   si1[RG], si2[RG];

    const int tid = threadIdx.x;
    const int rg  = blockIdx.x;
    const float* pb = part + (long)rg * KQ * (RG * K_DIM);

#pragma unroll
    for (int i = 0; i < (RG * K_DIM) / (BLOCK * 4); ++i) {      // 2 iters
        int f = tid + i * BLOCK;
        int r = f >> 4, c4 = (f & 15) * 4;
        float4 s = *(const float4*)(pb + 0 * (RG * K_DIM) + r * K_DIM + c4);
#pragma unroll
        for (int q = 1; q < KQ; ++q) {
            const float4 v = *(const float4*)(pb + q * (RG * K_DIM) + r * K_DIM + c4);
            s.x += v.x; s.y += v.y; s.z += v.z; s.w += v.w;
        }
        const float4 bv = *(const float4*)(bias + c4);
        lg[r][c4 + 0] = s.x + bv.x;
        lg[r][c4 + 1] = s.y + bv.y;
        lg[r][c4 + 2] = s.z + bv.z;
        lg[r][c4 + 3] = s.w + bv.w;
    }
    __syncthreads();

    // per-row top-2 (strict > , ascending scan = lowest-index tie-break) + softmax
    if (tid < RG) {
        float m1 = -INFINITY, m2 = -INFINITY;
        int i1 = 0, i2 = 0;
        for (int j = 0; j < K_DIM; ++j) {
            float v = lg[tid][j];
            if (v > m1)      { m2 = m1; i2 = i1; m1 = v; i1 = j; }
            else if (v > m2) { m2 = v; i2 = j; }
        }
        float e2  = expf(m2 - m1);
        float inv = 1.f / (1.f + e2);
        sa1[tid] = inv;
        sa2[tid] = e2 * inv;
        si1[tid] = i1; si2[tid] = i2;
    }
    __syncthreads();

    float* obase = out + (long)rg * (RG * K_DIM);
#pragma unroll
    for (int i = 0; i < (RG * K_DIM) / (BLOCK * 4); ++i) {      // 2 iters
        int f = tid + i * BLOCK;
        int r = f >> 4, j = (f & 15) * 4;
        int i1 = si1[r], i2 = si2[r];
        float a1 = sa1[r], a2 = sa2[r];
        float4 v;
        v.x = (j + 0 == i1) ? a1 : ((j + 0 == i2) ? a2 : 0.f);
        v.y = (j + 1 == i1) ? a1 : ((j + 1 == i2) ? a2 : 0.f);
        v.z = (j + 2 == i1) ? a1 : ((j + 2 == i2) ? a2 : 0.f);
        v.w = (j + 3 == i1) ? a1 : ((j + 3 == i2) ? a2 : 0.f);
        *(float4*)(obase + r * K_DIM + j) = v;
    }
}

extern "C" void kernel_launch(void* const* d_in, const int* in_sizes, int n_in,
                              void* d_out, int out_size, void* d_ws, size_t ws_size,
                              hipStream_t stream) {
    const float* z = (const float*)d_in[0];
    const float* W = (const float*)d_in[1];
    const float* b = (const float*)d_in[2];
    float* out  = (float*)d_out;
    float* part = (float*)d_ws;                  // 512 * 4096 fp32 = 8 MB
    const int N = in_sizes[0] / D_DIM;           // 8192
    const int nrg = N / RG;                      // 128
    gemm_partial<<<dim3(nrg * KQ), dim3(BLOCK), 0, stream>>>(z, W, part);
    reduce_topk <<<dim3(nrg),      dim3(BLOCK), 0, stream>>>(part, b, out);
}

// Round 4
// 219.348 us; speedup vs baseline: 5.7672x; 5.7672x over previous
//
#include <hip/hip_runtime.h>
#include <math.h>

// Router: logits = z @ W^T + b ; top-2 sparse softmax.  z:[8192,4096]f32,
// W:[64,4096]f32, b:[64], k=2.
//
// R4: MFMA via 3-limb bf16 split. Each fp32 x = xh+xm+xl (Dekker split, RNE
// bf16 limbs); 6 MFMA passes (hh,hm,mh,hl,lh,mm, accumulated smallest-first
// in fp32) give logit error in the same fp32-rounding class as the numpy
// reference -> top-2 selection risk identical to the passing R1-R3 kernels.
// R3 post-mortem: 128 un-fenced wave-uniform global loads/chunk got hoisted
// and spilled through scratch (FETCH 1.6GB/WRITE 2.6GB). Here all operand
// traffic is barrier-fenced LDS; global prefetch is 6 float4/thread only.
//
// Tiling: block=512thr(8 waves), M-tile 128 rows, N=64 cols, split-K x4.
// Grid 256 = 1 block/CU (LDS 83KB). Wave w: rows 16w..+15, 4 n-tiles.
// Frag layouts (HW-verified per guide): A[m=lane&15][k=quad*8+j],
// B[n=lane&15][k=quad*8+j], D[row=quad*4+reg][col=lane&15].
// LDS limb rows stride 72 shorts -> uniform bank spread for b128 frag reads.

typedef short bf16x8 __attribute__((ext_vector_type(8)));
typedef float f32x4  __attribute__((ext_vector_type(4)));

constexpr int D_DIM  = 4096;
constexpr int K_DIM  = 64;
constexpr int BM     = 128;            // rows per block
constexpr int CH     = 64;             // k per staged chunk
constexpr int KQ     = 4;              // split-K across blocks
constexpr int KRANGE = D_DIM / KQ;     // 1024
constexpr int NCH    = KRANGE / CH;    // 16
constexpr int BLOCK  = 512;
constexpr int LSTR   = 72;             // limb row stride in ushorts

__device__ __forceinline__ unsigned short bf16_rne(float f) {
    unsigned int u = __float_as_uint(f);
    u += 0x7FFFu + ((u >> 16) & 1u);
    return (unsigned short)(u >> 16);
}
__device__ __forceinline__ float bf16_f(unsigned short h) {
    return __uint_as_float(((unsigned int)h) << 16);
}

__global__ __launch_bounds__(BLOCK, 2) void gemm_mfma(
    const float* __restrict__ z, const float* __restrict__ W,
    float* __restrict__ part, int N)
{
    __shared__ __align__(16) unsigned short Az[3][BM][LSTR];     // 55.3 KB
    __shared__ __align__(16) unsigned short Bw[3][K_DIM][LSTR];  // 27.6 KB

    const int tid  = threadIdx.x;
    const int lane = tid & 63;
    const int wv   = tid >> 6;          // 0..7 : m-tile (rows 16*wv..+15)
    const int m16  = lane & 15;
    const int quad = lane >> 4;

    const int rgrp  = blockIdx.x >> 2;  // row group of 128
    const int kq    = blockIdx.x & 3;
    const long m0   = (long)rgrp * BM;
    const int kbase = kq * KRANGE;

    float4 zbuf[4], wbuf[2];
    // preload chunk 0 into registers
#pragma unroll
    for (int i = 0; i < 4; ++i) {
        int f = tid + i * BLOCK, r = f >> 4, k4 = (f & 15) * 4;
        zbuf[i] = *(const float4*)(z + (m0 + r) * (long)D_DIM + kbase + k4);
    }
#pragma unroll
    for (int i = 0; i < 2; ++i) {
        int f = tid + i * BLOCK, c = f >> 4, k4 = (f & 15) * 4;
        wbuf[i] = *(const float4*)(W + (long)c * D_DIM + kbase + k4);
    }

    f32x4 acc[4];
#pragma unroll
    for (int nt = 0; nt < 4; ++nt) acc[nt] = (f32x4){0.f, 0.f, 0.f, 0.f};

    for (int ch = 0; ch < NCH; ++ch) {
        // convert current regs -> 3 bf16 limb arrays in LDS
#pragma unroll
        for (int i = 0; i < 4; ++i) {
            int f = tid + i * BLOCK, r = f >> 4, k4 = (f & 15) * 4;
            unsigned short h[4], m[4], l[4];
            const float* p = (const float*)&zbuf[i];
#pragma unroll
            for (int j = 0; j < 4; ++j) {
                h[j] = bf16_rne(p[j]);
                float x1 = p[j] - bf16_f(h[j]);
                m[j] = bf16_rne(x1);
                l[j] = bf16_rne(x1 - bf16_f(m[j]));
            }
            *(ushort4*)&Az[0][r][k4] = make_ushort4(h[0], h[1], h[2], h[3]);
            *(ushort4*)&Az[1][r][k4] = make_ushort4(m[0], m[1], m[2], m[3]);
            *(ushort4*)&Az[2][r][k4] = make_ushort4(l[0], l[1], l[2], l[3]);
        }
#pragma unroll
        for (int i = 0; i < 2; ++i) {
            int f = tid + i * BLOCK, c = f >> 4, k4 = (f & 15) * 4;
            unsigned short h[4], m[4], l[4];
            const float* p = (const float*)&wbuf[i];
#pragma unroll
            for (int j = 0; j < 4; ++j) {
                h[j] = bf16_rne(p[j]);
                float x1 = p[j] - bf16_f(h[j]);
                m[j] = bf16_rne(x1);
                l[j] = bf16_rne(x1 - bf16_f(m[j]));
            }
            *(ushort4*)&Bw[0][c][k4] = make_ushort4(h[0], h[1], h[2], h[3]);
            *(ushort4*)&Bw[1][c][k4] = make_ushort4(m[0], m[1], m[2], m[3]);
            *(ushort4*)&Bw[2][c][k4] = make_ushort4(l[0], l[1], l[2], l[3]);
        }
        __syncthreads();

        // prefetch next chunk (stays in flight across the MFMA phase)
        if (ch + 1 < NCH) {
            const int k0 = kbase + (ch + 1) * CH;
#pragma unroll
            for (int i = 0; i < 4; ++i) {
                int f = tid + i * BLOCK, r = f >> 4, k4 = (f & 15) * 4;
                zbuf[i] = *(const float4*)(z + (m0 + r) * (long)D_DIM + k0 + k4);
            }
#pragma unroll
            for (int i = 0; i < 2; ++i) {
                int f = tid + i * BLOCK, c = f >> 4, k4 = (f & 15) * 4;
                wbuf[i] = *(const float4*)(W + (long)c * D_DIM + k0 + k4);
            }
        }

        // 6-pass MFMA, smallest magnitude first
        const int mrow = wv * 16 + m16;
#pragma unroll
        for (int ks2 = 0; ks2 < 2; ++ks2) {
            const int ko = ks2 * 32 + quad * 8;
            const bf16x8 ah = *(const bf16x8*)&Az[0][mrow][ko];
            const bf16x8 am = *(const bf16x8*)&Az[1][mrow][ko];
            const bf16x8 al = *(const bf16x8*)&Az[2][mrow][ko];
#pragma unroll
            for (int nt = 0; nt < 4; ++nt) {
                const int ncol = nt * 16 + m16;
                const bf16x8 bh = *(const bf16x8*)&Bw[0][ncol][ko];
                const bf16x8 bm = *(const bf16x8*)&Bw[1][ncol][ko];
                const bf16x8 bl = *(const bf16x8*)&Bw[2][ncol][ko];
                f32x4 a = acc[nt];
                a = __builtin_amdgcn_mfma_f32_16x16x32_bf16(al, bh, a, 0, 0, 0);
                a = __builtin_amdgcn_mfma_f32_16x16x32_bf16(am, bm, a, 0, 0, 0);
                a = __builtin_amdgcn_mfma_f32_16x16x32_bf16(ah, bl, a, 0, 0, 0);
                a = __builtin_amdgcn_mfma_f32_16x16x32_bf16(am, bh, a, 0, 0, 0);
                a = __builtin_amdgcn_mfma_f32_16x16x32_bf16(ah, bm, a, 0, 0, 0);
                a = __builtin_amdgcn_mfma_f32_16x16x32_bf16(ah, bh, a, 0, 0, 0);
                acc[nt] = a;
            }
        }
        __syncthreads();
    }

    // store partials: D[row=quad*4+r][col=m16] per 16x16 tile
#pragma unroll
    for (int nt = 0; nt < 4; ++nt) {
#pragma unroll
        for (int r = 0; r < 4; ++r) {
            long row = m0 + wv * 16 + quad * 4 + r;
            int  col = nt * 16 + m16;
            part[((long)kq * N + row) * K_DIM + col] = acc[nt][r];
        }
    }
}

constexpr int RG2  = 32;
constexpr int BLK2 = 256;

__global__ __launch_bounds__(BLK2) void reduce_topk(
    const float* __restrict__ part, const float* __restrict__ bias,
    float* __restrict__ out, int N)
{
    __shared__ float lg[RG2][K_DIM + 1];
    __shared__ float sa1[RG2], sa2[RG2];
    __shared__ int   si1[RG2], si2[RG2];

    const int tid = threadIdx.x;
    const long r0 = (long)blockIdx.x * RG2;

#pragma unroll
    for (int i = 0; i < (RG2 * K_DIM) / (BLK2 * 4); ++i) {       // 2 iters
        int f = tid + i * BLK2, r = f >> 4, c4 = (f & 15) * 4;
        float4 s = *(const float4*)(part + (r0 + r) * K_DIM + c4);
#pragma unroll
        for (int q = 1; q < KQ; ++q) {
            const float4 v = *(const float4*)(part + ((long)q * N + r0 + r) * K_DIM + c4);
            s.x += v.x; s.y += v.y; s.z += v.z; s.w += v.w;
        }
        const float4 bv = *(const float4*)(bias + c4);
        lg[r][c4 + 0] = s.x + bv.x;
        lg[r][c4 + 1] = s.y + bv.y;
        lg[r][c4 + 2] = s.z + bv.z;
        lg[r][c4 + 3] = s.w + bv.w;
    }
    __syncthreads();

    if (tid < RG2) {   // strict >, ascending scan = lowest-index tie-break
        float m1 = -INFINITY, m2 = -INFINITY;
        int i1 = 0, i2 = 0;
        for (int j = 0; j < K_DIM; ++j) {
            float v = lg[tid][j];
            if (v > m1)      { m2 = m1; i2 = i1; m1 = v; i1 = j; }
            else if (v > m2) { m2 = v; i2 = j; }
        }
        float e2  = expf(m2 - m1);
        float inv = 1.f / (1.f + e2);
        sa1[tid] = inv; sa2[tid] = e2 * inv;
        si1[tid] = i1;  si2[tid] = i2;
    }
    __syncthreads();

    float* obase = out + r0 * K_DIM;
#pragma unroll
    for (int i = 0; i < (RG2 * K_DIM) / (BLK2 * 4); ++i) {       // 2 iters
        int f = tid + i * BLK2, r = f >> 4, j = (f & 15) * 4;
        int i1 = si1[r], i2 = si2[r];
        float a1 = sa1[r], a2 = sa2[r];
        float4 v;
        v.x = (j + 0 == i1) ? a1 : ((j + 0 == i2) ? a2 : 0.f);
        v.y = (j + 1 == i1) ? a1 : ((j + 1 == i2) ? a2 : 0.f);
        v.z = (j + 2 == i1) ? a1 : ((j + 2 == i2) ? a2 : 0.f);
        v.w = (j + 3 == i1) ? a1 : ((j + 3 == i2) ? a2 : 0.f);
        *(float4*)(obase + (long)r * K_DIM + j) = v;
    }
}

extern "C" void kernel_launch(void* const* d_in, const int* in_sizes, int n_in,
                              void* d_out, int out_size, void* d_ws, size_t ws_size,
                              hipStream_t stream) {
    const float* z = (const float*)d_in[0];
    const float* W = (const float*)d_in[1];
    const float* b = (const float*)d_in[2];
    float* out  = (float*)d_out;
    float* part = (float*)d_ws;                  // KQ * N * 64 fp32 = 8 MB
    const int N = in_sizes[0] / D_DIM;           // 8192
    gemm_mfma  <<<dim3((N / BM) * KQ), dim3(BLOCK), 0, stream>>>(z, W, part, N);
    reduce_topk<<<dim3(N / RG2),       dim3(BLK2), 0, stream>>>(part, b, out, N);
}

// Round 5
// 212.449 us; speedup vs baseline: 5.9545x; 1.0325x over previous
//
#include <hip/hip_runtime.h>
#include <math.h>

// Router: logits = z @ W^T + b ; top-2 sparse softmax.  z:[8192,4096]f32,
// W:[64,4096]f32, b:[64], k=2.
//
// R5: fp16 2-limb MFMA (was bf16 3-limb). x = h + l*2^-11 with h,l fp16 RNE
// (l pre-scaled by 2^11 -> no denormals); 3 MFMA passes (hh into acc_hi,
// h*l' + l'*h into acc_lo, recombined *2^-11). Per-product error ~2^-22 =
// fp32 class (same as passing R1-R3), so top-2 selection risk unchanged.
// R4 post-mortem: LDS-pipe bound (240 ds_read_b128 + 9K b64 writes per
// CU-chunk, 1 block/CU at 83 KB LDS, barriers exposed at 2 waves/SIMD).
// Now: 2 limbs (-33% LDS traffic), BM=64 -> 37 KB LDS -> 2 blocks/CU,
// 16 waves/CU, independent barriers overlap. Grid 512 = one full round.
// Frag layouts identical to R4's verified ones (shape-determined):
// A[m=lane&15][k=quad*8+j], B[n=lane&15][k=quad*8+j], D[row=quad*4+reg][col=lane&15].

typedef _Float16 f16x8 __attribute__((ext_vector_type(8)));
typedef _Float16 f16x4 __attribute__((ext_vector_type(4)));
typedef float    f32x4 __attribute__((ext_vector_type(4)));

constexpr int D_DIM  = 4096;
constexpr int K_DIM  = 64;
constexpr int BM     = 64;             // rows per block
constexpr int CH     = 64;             // k per staged chunk
constexpr int KQ     = 4;              // split-K across blocks
constexpr int KRANGE = D_DIM / KQ;     // 1024
constexpr int NCH    = KRANGE / CH;    // 16
constexpr int BLOCK  = 512;
constexpr int LSTR   = 72;             // limb row stride in f16 elems (144 B, 16B-aligned)

__global__ __launch_bounds__(BLOCK, 4) void gemm_f16limb(
    const float* __restrict__ z, const float* __restrict__ W,
    float* __restrict__ part, int N)
{
    __shared__ __align__(16) _Float16 Az[2][BM][LSTR];     // 18.4 KB
    __shared__ __align__(16) _Float16 Bw[2][K_DIM][LSTR];  // 18.4 KB -> 36.9 KB total

    const int tid  = threadIdx.x;
    const int lane = tid & 63;
    const int wv   = tid >> 6;          // 0..7
    const int mt   = wv >> 1;           // m-tile 0..3 (16 rows each)
    const int nh   = wv & 1;            // n-half 0..1 (2 n-tiles each)
    const int m16  = lane & 15;
    const int quad = lane >> 4;

    const int rgrp  = blockIdx.x >> 2;
    const int kq    = blockIdx.x & 3;
    const long m0   = (long)rgrp * BM;
    const int kbase = kq * KRANGE;

    float4 zb[2], wb[2];
#pragma unroll
    for (int i = 0; i < 2; ++i) {
        int f = tid + i * BLOCK, r = f >> 4, k4 = (f & 15) * 4;
        zb[i] = *(const float4*)(z + (m0 + r) * (long)D_DIM + kbase + k4);
        wb[i] = *(const float4*)(W + (long)r * D_DIM + kbase + k4);
    }

    f32x4 acch[2], accl[2];
#pragma unroll
    for (int t = 0; t < 2; ++t) {
        acch[t] = (f32x4){0.f, 0.f, 0.f, 0.f};
        accl[t] = (f32x4){0.f, 0.f, 0.f, 0.f};
    }

    for (int ch = 0; ch < NCH; ++ch) {
        // convert current regs -> 2 fp16 limb arrays in LDS (low limb *2^11)
#pragma unroll
        for (int i = 0; i < 2; ++i) {
            int f = tid + i * BLOCK, r = f >> 4, k4 = (f & 15) * 4;
            const float* pz = (const float*)&zb[i];
            const float* pw = (const float*)&wb[i];
            f16x4 zh, zl, wh, wl;
#pragma unroll
            for (int j = 0; j < 4; ++j) {
                _Float16 h = (_Float16)pz[j];
                zh[j] = h;
                zl[j] = (_Float16)((pz[j] - (float)h) * 2048.0f);
                _Float16 g = (_Float16)pw[j];
                wh[j] = g;
                wl[j] = (_Float16)((pw[j] - (float)g) * 2048.0f);
            }
            *(f16x4*)&Az[0][r][k4] = zh;
            *(f16x4*)&Az[1][r][k4] = zl;
            *(f16x4*)&Bw[0][r][k4] = wh;
            *(f16x4*)&Bw[1][r][k4] = wl;
        }
        __syncthreads();

        // prefetch next chunk (few regs, barrier-fenced -> no hoist/spill)
        if (ch + 1 < NCH) {
            const int k0 = kbase + (ch + 1) * CH;
#pragma unroll
            for (int i = 0; i < 2; ++i) {
                int f = tid + i * BLOCK, r = f >> 4, k4 = (f & 15) * 4;
                zb[i] = *(const float4*)(z + (m0 + r) * (long)D_DIM + k0 + k4);
                wb[i] = *(const float4*)(W + (long)r * D_DIM + k0 + k4);
            }
        }

        const int mrow = mt * 16 + m16;
#pragma unroll
        for (int ks = 0; ks < 2; ++ks) {
            const int ko = ks * 32 + quad * 8;
            const f16x8 ah = *(const f16x8*)&Az[0][mrow][ko];
            const f16x8 al = *(const f16x8*)&Az[1][mrow][ko];
#pragma unroll
            for (int t = 0; t < 2; ++t) {
                const int ncol = (nh * 2 + t) * 16 + m16;
                const f16x8 bh = *(const f16x8*)&Bw[0][ncol][ko];
                const f16x8 bl = *(const f16x8*)&Bw[1][ncol][ko];
                accl[t] = __builtin_amdgcn_mfma_f32_16x16x32_f16(al, bh, accl[t], 0, 0, 0);
                accl[t] = __builtin_amdgcn_mfma_f32_16x16x32_f16(ah, bl, accl[t], 0, 0, 0);
                acch[t] = __builtin_amdgcn_mfma_f32_16x16x32_f16(ah, bh, acch[t], 0, 0, 0);
            }
        }
        __syncthreads();
    }

    // partial store: D[row=quad*4+r][col], recombine limbs
#pragma unroll
    for (int t = 0; t < 2; ++t) {
#pragma unroll
        for (int r = 0; r < 4; ++r) {
            long row = m0 + mt * 16 + quad * 4 + r;
            int  col = (nh * 2 + t) * 16 + m16;
            part[((long)kq * N + row) * K_DIM + col] =
                acch[t][r] + accl[t][r] * 4.8828125e-4f;   // 2^-11
        }
    }
}

constexpr int RG2  = 32;
constexpr int BLK2 = 256;

__global__ __launch_bounds__(BLK2) void reduce_topk(
    const float* __restrict__ part, const float* __restrict__ bias,
    float* __restrict__ out, int N)
{
    __shared__ float lg[RG2][K_DIM + 1];
    __shared__ float sa1[RG2], sa2[RG2];
    __shared__ int   si1[RG2], si2[RG2];

    const int tid = threadIdx.x;
    const long r0 = (long)blockIdx.x * RG2;

#pragma unroll
    for (int i = 0; i < (RG2 * K_DIM) / (BLK2 * 4); ++i) {       // 2 iters
        int f = tid + i * BLK2, r = f >> 4, c4 = (f & 15) * 4;
        float4 s = *(const float4*)(part + (r0 + r) * K_DIM + c4);
#pragma unroll
        for (int q = 1; q < KQ; ++q) {
            const float4 v = *(const float4*)(part + ((long)q * N + r0 + r) * K_DIM + c4);
            s.x += v.x; s.y += v.y; s.z += v.z; s.w += v.w;
        }
        const float4 bv = *(const float4*)(bias + c4);
        lg[r][c4 + 0] = s.x + bv.x;
        lg[r][c4 + 1] = s.y + bv.y;
        lg[r][c4 + 2] = s.z + bv.z;
        lg[r][c4 + 3] = s.w + bv.w;
    }
    __syncthreads();

    if (tid < RG2) {   // strict >, ascending scan = lowest-index tie-break
        float m1 = -INFINITY, m2 = -INFINITY;
        int i1 = 0, i2 = 0;
        for (int j = 0; j < K_DIM; ++j) {
            float v = lg[tid][j];
            if (v > m1)      { m2 = m1; i2 = i1; m1 = v; i1 = j; }
            else if (v > m2) { m2 = v; i2 = j; }
        }
        float e2  = expf(m2 - m1);
        float inv = 1.f / (1.f + e2);
        sa1[tid] = inv; sa2[tid] = e2 * inv;
        si1[tid] = i1;  si2[tid] = i2;
    }
    __syncthreads();

    float* obase = out + r0 * K_DIM;
#pragma unroll
    for (int i = 0; i < (RG2 * K_DIM) / (BLK2 * 4); ++i) {       // 2 iters
        int f = tid + i * BLK2, r = f >> 4, j = (f & 15) * 4;
        int i1 = si1[r], i2 = si2[r];
        float a1 = sa1[r], a2 = sa2[r];
        float4 v;
        v.x = (j + 0 == i1) ? a1 : ((j + 0 == i2) ? a2 : 0.f);
        v.y = (j + 1 == i1) ? a1 : ((j + 1 == i2) ? a2 : 0.f);
        v.z = (j + 2 == i1) ? a1 : ((j + 2 == i2) ? a2 : 0.f);
        v.w = (j + 3 == i1) ? a1 : ((j + 3 == i2) ? a2 : 0.f);
        *(float4*)(obase + (long)r * K_DIM + j) = v;
    }
}

extern "C" void kernel_launch(void* const* d_in, const int* in_sizes, int n_in,
                              void* d_out, int out_size, void* d_ws, size_t ws_size,
                              hipStream_t stream) {
    const float* z = (const float*)d_in[0];
    const float* W = (const float*)d_in[1];
    const float* b = (const float*)d_in[2];
    float* out  = (float*)d_out;
    float* part = (float*)d_ws;                  // KQ * N * 64 fp32 = 8 MB
    const int N = in_sizes[0] / D_DIM;           // 8192
    gemm_f16limb<<<dim3((N / BM) * KQ), dim3(BLOCK), 0, stream>>>(z, W, part, N);
    reduce_topk <<<dim3(N / RG2),       dim3(BLK2), 0, stream>>>(part, b, out, N);
}